// Round 13
// baseline (129.399 us; speedup 1.0000x reference)
//
#include <hip/hip_runtime.h>
#include <hip/hip_bf16.h>
#include <cmath>

#define Bb   2
#define Tseq 2048
#define NH   16
#define DM   1024

using f32x4 = __attribute__((ext_vector_type(4))) float;
using s16x8 = __attribute__((ext_vector_type(8))) short;
using s16x4 = __attribute__((ext_vector_type(4))) short;

typedef const __attribute__((address_space(1))) unsigned char* as1p;
typedef __attribute__((address_space(3))) unsigned char* as3p;

static __device__ __forceinline__ void gload_lds16(const void* g, void* l){
  __builtin_amdgcn_global_load_lds((as1p)g, (as3p)l, 16, 0, 0);
}

// PV MFMA: 16x16x16 bf16 (K=16). B-frag needs P[k=g*4+j][q=ln] == QK^T output s[nt][r].
#if defined(__has_builtin)
#if __has_builtin(__builtin_amdgcn_mfma_f32_16x16x16bf16_1k)
#define MFMA16(acc, va, pb) (acc) = __builtin_amdgcn_mfma_f32_16x16x16bf16_1k((va), (pb), (acc), 0, 0, 0)
#endif
#endif
#ifndef MFMA16
#define MFMA16(acc, va, pb) asm volatile("s_nop 1\n\tv_mfma_f32_16x16x16_bf16 %0, %1, %2, %0" : "+v"(acc) : "v"(va), "v"(pb))
#endif

static __device__ __forceinline__ float b2f(unsigned short u){
  union { unsigned int u; float f; } v; v.u = ((unsigned int)u) << 16; return v.f;
}
static __device__ __forceinline__ unsigned short f2b(float f){
  union { float f; unsigned int u; } v; v.f = f;
  unsigned int u = v.u;
  return (unsigned short)((u + 0x7fffu + ((u >> 16) & 1u)) >> 16);
}

// ---------------- fp32 -> bf16 convert ----------------
__global__ void k_convert(const float* __restrict__ in, unsigned short* __restrict__ out, int n){
  int stride = gridDim.x * blockDim.x;
  for (int i = blockIdx.x * blockDim.x + threadIdx.x; i * 4 < n; i += stride) {
    const float4 v = *reinterpret_cast<const float4*>(in + (size_t)i * 4);
    ushort4 o; o.x = f2b(v.x); o.y = f2b(v.y); o.z = f2b(v.z); o.w = f2b(v.w);
    *reinterpret_cast<ushort4*>(out + (size_t)i * 4) = o;
  }
}

// ---------------- GEMM  C[m,n] = sum_k A[m,k] * W[n,k] ----------------
// BK=64, gload_lds w16 with pre-swizzled SOURCE (linear dest + inverse-swz src
// + swz read; 0 bank conflicts verified r11). XCD-chunked 1D grid.
// MODE 0: fp32 C out. MODE 2: qkv fused epilogue -- q/k get in-register RoPE
// (on-the-fly __sincosf); q scaled by 0.125*log2(e) so attn can use exp2.
template<int MODE>
__global__ __launch_bounds__(256) void k_gemm_bt(const unsigned short* __restrict__ A,
                                                 const unsigned short* __restrict__ W,
                                                 void* __restrict__ Cout,
                                                 int M, int N, int K, int NYL,
                                                 unsigned short* __restrict__ qr,
                                                 unsigned short* __restrict__ kr){
  __shared__ unsigned short As[128*64];
  __shared__ unsigned short Bs[128*64];
  const int i = (int)blockIdx.x;
  const int xcd = i & 7, rr = i >> 3;
  const int bx = rr / NYL, by = xcd * NYL + (rr % NYL);
  const int bm = bx * 128, bn = by * 128;
  const int tid = threadIdx.x;
  const int lane = tid & 63, w = tid >> 6;
  const int wr = w >> 1, wc = w & 1;            // wave -> 64x64 quadrant
  const int g = lane >> 4, ln = lane & 15;
  f32x4 acc[4][4] = {};
  char* asb = (char*)As + w * 4096;
  char* bsb = (char*)Bs + w * 4096;
  const int lrow8 = lane >> 3;                   // 0..7: row within 8-row gload group
  const int kcolb = ((lane & 7) ^ lrow8) * 16;   // byte col in 128B row window, pre-swz
  const size_t aro = (size_t)(bm + w * 32 + lrow8) * K;
  const size_t bro = (size_t)(bn + w * 32 + lrow8) * K;
  const int xr = (ln & 7) << 4;                  // read-side XOR (row&7 == ln&7)
  for (int k0 = 0; k0 < K; k0 += 64) {
    #pragma unroll
    for (int q4 = 0; q4 < 4; ++q4) {
      gload_lds16((const char*)(A + aro + (size_t)(q4 * 8) * K + k0) + kcolb, asb + q4 * 1024);
      gload_lds16((const char*)(W + bro + (size_t)(q4 * 8) * K + k0) + kcolb, bsb + q4 * 1024);
    }
    __syncthreads();
    #pragma unroll
    for (int kk = 0; kk < 2; ++kk) {
      s16x8 af[4], bfr[4];
      const int ro = (kk * 64 + g * 16) ^ xr;
      #pragma unroll
      for (int mt = 0; mt < 4; ++mt)
        af[mt] = *reinterpret_cast<const s16x8*>((char*)As + (wr*64 + mt*16 + ln) * 128 + ro);
      #pragma unroll
      for (int nt = 0; nt < 4; ++nt)
        bfr[nt] = *reinterpret_cast<const s16x8*>((char*)Bs + (wc*64 + nt*16 + ln) * 128 + ro);
      #pragma unroll
      for (int mt = 0; mt < 4; ++mt)
        #pragma unroll
        for (int nt = 0; nt < 4; ++nt)
          acc[mt][nt] = __builtin_amdgcn_mfma_f32_16x16x32_bf16(af[mt], bfr[nt], acc[mt][nt], 0, 0, 0);
    }
    __syncthreads();
  }
  // ---------------- epilogue ----------------
  if (MODE == 0) {
    #pragma unroll
    for (int mt = 0; mt < 4; ++mt)
      #pragma unroll
      for (int nt = 0; nt < 4; ++nt)
        #pragma unroll
        for (int r = 0; r < 4; ++r) {
          int row = bm + wr*64 + mt*16 + g*4 + r;     // D: row = (lane>>4)*4 + reg
          int col = bn + wc*64 + nt*16 + ln;          // D: col = lane&15
          reinterpret_cast<float*>(Cout)[(size_t)row * N + col] = acc[mt][nt][r];
        }
  } else {
    const int region = bn >> 10;                      // 0=q, 1=k, 2=v
    if (region == 2) {
      #pragma unroll
      for (int mt = 0; mt < 4; ++mt)
        #pragma unroll
        for (int nt = 0; nt < 4; ++nt)
          #pragma unroll
          for (int r = 0; r < 4; ++r) {
            int row = bm + wr*64 + mt*16 + g*4 + r;
            int col = bn + wc*64 + nt*16 + ln;
            reinterpret_cast<unsigned short*>(Cout)[(size_t)row * N + col] = f2b(acc[mt][nt][r]);
          }
    } else {
      // RoPE in-register: dd = nt*16+ln (wc-independent); pairs (nt, nt^2) same lane.
      const float if0 = exp2f(-(float)ln        * 0.4152410118074f);
      const float if1 = exp2f(-(float)(16 + ln) * 0.4152410118074f);
      const int h = ((bn + wc * 64) >> 6) & 15;
      unsigned short* dst = (region == 0) ? qr : kr;
      // q: fold 1/sqrt(dh) AND log2(e) so attention uses native exp2
      const float qs = (region == 0) ? 0.18033688011112042f : 1.0f;
      #pragma unroll
      for (int mt = 0; mt < 4; ++mt)
        #pragma unroll
        for (int r = 0; r < 4; ++r) {
          int row = bm + wr*64 + mt*16 + g*4 + r;
          int t = row & (Tseq - 1), b = row >> 11;
          float c0, s0, c1, s1;
          __sincosf((float)t * if0, &s0, &c0);
          __sincosf((float)t * if1, &s1, &c1);
          float v0 = (acc[mt][0][r] * c0 - acc[mt][2][r] * s0) * qs;  // dd=ln
          float v1 = (acc[mt][1][r] * c1 - acc[mt][3][r] * s1) * qs;  // dd=16+ln
          float v2 = (acc[mt][2][r] * c0 + acc[mt][0][r] * s0) * qs;  // dd=32+ln
          float v3 = (acc[mt][3][r] * c1 + acc[mt][1][r] * s1) * qs;  // dd=48+ln
          size_t base = ((size_t)(b * NH + h) * Tseq + t) * 64 + ln;
          dst[base]      = f2b(v0);
          dst[base + 16] = f2b(v1);
          dst[base + 32] = f2b(v2);
          dst[base + 48] = f2b(v3);
        }
    }
  }
}

// ---------------- V transpose: qkv[b,t,2048+h*64+d] -> vt[b,h,d,t], LDS-tiled ----------------
__global__ __launch_bounds__(256) void k_vtrans(const unsigned short* __restrict__ qkv,
                                                unsigned short* __restrict__ vt){
  __shared__ unsigned short L[64*72];               // stride 72 shorts (144B, 16B-aligned)
  const int blk = blockIdx.x;                       // bh*32 + ttile
  const int tt64 = blk & 31, bh = blk >> 5;
  const int b = bh >> 4, h = bh & 15;
  const int t0 = tt64 * 64;
  const int tid = threadIdx.x;
  {
    const int tr = tid >> 2, c = tid & 3;           // row t, 16-short chunk
    const unsigned short* src = qkv + ((size_t)(b * Tseq) + t0 + tr) * 3072 + 2048 + h * 64 + c * 16;
    uint4 a0 = *reinterpret_cast<const uint4*>(src);
    uint4 a1 = *reinterpret_cast<const uint4*>(src + 8);
    *reinterpret_cast<uint4*>(&L[tr * 72 + c * 16])     = a0;
    *reinterpret_cast<uint4*>(&L[tr * 72 + c * 16 + 8]) = a1;
  }
  __syncthreads();
  {
    const int d = tid >> 2, c = tid & 3;            // row d, 16-t chunk
    unsigned int wq[8];
    #pragma unroll
    for (int j = 0; j < 8; ++j) {
      unsigned int lo = L[(c * 16 + 2 * j)     * 72 + d];
      unsigned int hi = L[(c * 16 + 2 * j + 1) * 72 + d];
      wq[j] = lo | (hi << 16);
    }
    unsigned short* dst = vt + ((size_t)bh * 64 + d) * Tseq + t0 + c * 16;
    *reinterpret_cast<uint4*>(dst)     = make_uint4(wq[0], wq[1], wq[2], wq[3]);
    *reinterpret_cast<uint4*>(dst + 8) = make_uint4(wq[4], wq[5], wq[6], wq[7]);
  }
}

// ---------------- causal flash attention, fully-swapped, dbuf + reg-P ----------------
// 256-thr blocks (4 waves x 16 q), paired q-tiles (j, 31-j): 33 visits, 512 blocks
// = 2/CU, XCD-chunked (4 heads/XCD L2-resident). K staged via global_load_lds
// (pre-swizzled source); V reg-staged with fine swizzle ((row&7)<<4 | row&8) so
// PV b64 reads cover all 16 bank-pairs per 16-lane quarter (conflict-free).
// QK^T: 16x16x32 swapped. PV: 16x16x16, P in registers (exp2 + trunc-pack).
__global__ __launch_bounds__(256, 2) void k_attn(const unsigned short* __restrict__ Qr,
                                                 const unsigned short* __restrict__ Kr,
                                                 const unsigned short* __restrict__ Vt,
                                                 unsigned short* __restrict__ Ao){
  __shared__ unsigned short Ks[2][64*64];
  __shared__ unsigned short Vs[2][64*64];
  __shared__ unsigned short Ps[4][16*72];
  // XCD-chunked bijective remap: 512 = 8 xcds x (4 heads x 16 pj)
  const int i = (int)blockIdx.x;
  const int xcd = i & 7, r = i >> 3;
  const int bh = xcd * 4 + (r >> 4);
  const int pj = r & 15;
  const unsigned short* Q  = Qr + (size_t)bh * Tseq * 64;
  const unsigned short* Kp = Kr + (size_t)bh * Tseq * 64;
  const unsigned short* Vp = Vt + (size_t)bh * 64 * Tseq;
  const int tid = threadIdx.x;
  const int w = tid >> 6, lane = tid & 63;
  const int g = lane >> 4, ln = lane & 15;
  // K staging (gload_lds): lane -> row lane>>3 (8 rows/instr), pre-swizzled col
  const int klr = lane >> 3;
  const int klc = ((lane & 7) ^ klr) * 8;           // shorts
  // V staging (reg): row = tid>>2, 32B at byte col c2*16; fine swizzle incl. bit3
  const int srow = tid >> 2;
  const int c2 = (tid & 3) * 2;
  const int scol = c2 * 8;                          // shorts
  const int vswz = ((srow & 7) << 4) | (srow & 8);
  const int vb0 = srow * 128 + ((c2 * 16)      ^ vswz);
  const int vb1 = srow * 128 + ((c2 * 16 + 8)  ^ vswz);
  const int vb2 = srow * 128 + ((c2 * 16 + 16) ^ vswz);
  const int vb3 = srow * 128 + ((c2 * 16 + 24) ^ vswz);
  // QK frag read offsets (K buffer, 16B-granular swizzle)
  const int x0 = (g * 16)      ^ ((ln & 7) << 4);
  const int x1 = (64 + g * 16) ^ ((ln & 7) << 4);
  // PV frag read swizzle (V buffer, fine)
  const int pvswz = ((ln & 7) << 4) | (ln & 8);
  unsigned short* Pw = Ps[w];
  const int b = bh / NH, h = bh % NH;

  #pragma unroll
  for (int pass = 0; pass < 2; ++pass) {
    const int j = pass ? (31 - pj) : pj;            // paired q-tiles: 33 visits total
    const int q0 = j * 64;
    const int ntiles = j + 1;
    const int q0w = q0 + w * 16;

    s16x8 qf0 = *reinterpret_cast<const s16x8*>(&Q[(size_t)(q0w + ln) * 64 + g * 8]);
    s16x8 qf1 = *reinterpret_cast<const s16x8*>(&Q[(size_t)(q0w + ln) * 64 + 32 + g * 8]);

    f32x4 oacc[4] = {};
    float lsum = 0.f;

    // prologue: stage tile 0 into buf 0
    {
      const unsigned short* gk = Kp + (size_t)(w * 16 + klr) * 64 + klc;
      gload_lds16(gk,       (char*)Ks[0] + w * 2048);
      gload_lds16(gk + 512, (char*)Ks[0] + w * 2048 + 1024);      // +8 rows
      const unsigned short* gv = Vp + (size_t)srow * Tseq + scol;
      uint4 v0 = *reinterpret_cast<const uint4*>(gv);
      uint4 v1 = *reinterpret_cast<const uint4*>(gv + 8);
      *reinterpret_cast<uint2*>((char*)Vs[0] + vb0) = make_uint2(v0.x, v0.y);
      *reinterpret_cast<uint2*>((char*)Vs[0] + vb1) = make_uint2(v0.z, v0.w);
      *reinterpret_cast<uint2*>((char*)Vs[0] + vb2) = make_uint2(v1.x, v1.y);
      *reinterpret_cast<uint2*>((char*)Vs[0] + vb3) = make_uint2(v1.z, v1.w);
    }
    __syncthreads();
    int cur = 0;

    for (int kt = 0; kt < ntiles; ++kt) {
      const bool pre = (kt + 1 < ntiles);
      const int nxt = cur ^ 1;
      uint4 nv0, nv1;
      if (pre) {  // K: async direct-to-LDS into free buffer; V: issue loads early
        const unsigned short* gk = Kp + (size_t)((kt + 1) * 64 + w * 16 + klr) * 64 + klc;
        gload_lds16(gk,       (char*)Ks[nxt] + w * 2048);
        gload_lds16(gk + 512, (char*)Ks[nxt] + w * 2048 + 1024);
        const unsigned short* gv = Vp + (size_t)srow * Tseq + (kt + 1) * 64 + scol;
        nv0 = *reinterpret_cast<const uint4*>(gv);
        nv1 = *reinterpret_cast<const uint4*>(gv + 8);
      }
      // ---- QK^T swapped: s[nt] = S^T[k = kt*64+nt*16+g*4+r][q = q0w+ln] ----
      f32x4 s[4] = {};
      const char* kb = (const char*)Ks[cur];
      __builtin_amdgcn_s_setprio(1);
      #pragma unroll
      for (int nt = 0; nt < 4; ++nt) {
        s16x8 kfa = *reinterpret_cast<const s16x8*>(kb + nt * 2048 + ln * 128 + x0);
        s16x8 kfb = *reinterpret_cast<const s16x8*>(kb + nt * 2048 + ln * 128 + x1);
        s[nt] = __builtin_amdgcn_mfma_f32_16x16x32_bf16(kfa, qf0, s[nt], 0, 0, 0);
        s[nt] = __builtin_amdgcn_mfma_f32_16x16x32_bf16(kfb, qf1, s[nt], 0, 0, 0);
      }
      __builtin_amdgcn_s_setprio(0);
      // ---- causal mask (last tile only; k_rel = nt*16+g*4+r, q_rel = w*16+ln) ----
      if (kt == ntiles - 1) {
        #pragma unroll
        for (int nt = 0; nt < 4; ++nt)
          #pragma unroll
          for (int r2 = 0; r2 < 4; ++r2)
            if (nt * 16 + g * 4 + r2 > w * 16 + ln) s[nt][r2] = -1e30f;
      }
      // ---- fixed-base softmax in exp2 domain (q pre-scaled by log2e/8);
      //      P packed to bf16 by truncation (P-only; tolerance has 5x headroom) ----
      s16x4 pb[4];
      #pragma unroll
      for (int nt = 0; nt < 4; ++nt)
        #pragma unroll
        for (int r2 = 0; r2 < 4; ++r2) {
          float p = exp2f(s[nt][r2]);
          lsum += p;
          pb[nt][r2] = (short)(__float_as_uint(p) >> 16);
        }
      // ---- PV via 16x16x16: oacc[dt] = O^T[d = dt*16+g*4+r][q = ln] ----
      const char* vb = (const char*)Vs[cur];
      __builtin_amdgcn_s_setprio(1);
      #pragma unroll
      for (int dt = 0; dt < 4; ++dt) {
        #pragma unroll
        for (int nt = 0; nt < 4; ++nt) {
          s16x4 va = *reinterpret_cast<const s16x4*>(vb + (dt * 16 + ln) * 128 + ((nt * 32 + g * 8) ^ pvswz));
          MFMA16(oacc[dt], va, pb[nt]);
        }
      }
      __builtin_amdgcn_s_setprio(0);
      // ---- write prefetched V into other buffer; single barrier ----
      if (pre) {
        *reinterpret_cast<uint2*>((char*)Vs[nxt] + vb0) = make_uint2(nv0.x, nv0.y);
        *reinterpret_cast<uint2*>((char*)Vs[nxt] + vb1) = make_uint2(nv0.z, nv0.w);
        *reinterpret_cast<uint2*>((char*)Vs[nxt] + vb2) = make_uint2(nv1.x, nv1.y);
        *reinterpret_cast<uint2*>((char*)Vs[nxt] + vb3) = make_uint2(nv1.z, nv1.w);
      }
      __syncthreads();
      cur ^= 1;
    }

    // ---- epilogue: l-reduce, O^T -> row-major via LDS bounce, coalesced stores ----
    float l = lsum;
    l += __shfl_xor(l, 16);
    l += __shfl_xor(l, 32);
    float inv = 1.f / l;
    #pragma unroll
    for (int nt = 0; nt < 4; ++nt) {
      unsigned int lo = (unsigned int)f2b(oacc[nt][0] * inv) | ((unsigned int)f2b(oacc[nt][1] * inv) << 16);
      unsigned int hi = (unsigned int)f2b(oacc[nt][2] * inv) | ((unsigned int)f2b(oacc[nt][3] * inv) << 16);
      *reinterpret_cast<uint2*>(&Pw[ln * 72 + nt * 16 + g * 4]) = make_uint2(lo, hi);
    }
    asm volatile("s_waitcnt lgkmcnt(0)" ::: "memory");
    __builtin_amdgcn_sched_barrier(0);
    const int rr = lane >> 2;                 // 0..15: q-row within wave tile
    const int cc = (lane & 3) * 8;            // short offset
    uint4 ov0 = *reinterpret_cast<const uint4*>(&Pw[rr * 72 + cc]);
    uint4 ov1 = *reinterpret_cast<const uint4*>(&Pw[rr * 72 + cc + 32]);
    int t = q0w + rr;
    unsigned short* orow = &Ao[((size_t)(b * Tseq + t) * DM) + h * 64];
    *reinterpret_cast<uint4*>(orow + cc)      = ov0;
    *reinterpret_cast<uint4*>(orow + cc + 32) = ov1;
  }
}

extern "C" void kernel_launch(void* const* d_in, const int* in_sizes, int n_in,
                              void* d_out, int out_size, void* d_ws, size_t ws_size,
                              hipStream_t stream) {
  const float* x    = (const float*)d_in[0];
  const float* qkvw = (const float*)d_in[1];
  const float* outw = (const float*)d_in[2];
  float* out = (float*)d_out;
  char* ws = (char*)d_ws;
  size_t off = 0;
  auto alloc = [&](size_t bytes)->void*{ void* p = ws + off; off += (bytes + 255) & ~(size_t)255; return p; };
  unsigned short* x_bf   = (unsigned short*)alloc((size_t)Bb*Tseq*DM*2);
  unsigned short* qw_bf  = (unsigned short*)alloc((size_t)3*DM*DM*2);
  unsigned short* ow_bf  = (unsigned short*)alloc((size_t)DM*DM*2);
  unsigned short* qkv_bf = (unsigned short*)alloc((size_t)Bb*Tseq*3*DM*2);
  unsigned short* qr     = (unsigned short*)alloc((size_t)Bb*NH*Tseq*64*2);
  unsigned short* kr     = (unsigned short*)alloc((size_t)Bb*NH*Tseq*64*2);
  unsigned short* vt     = (unsigned short*)alloc((size_t)Bb*NH*Tseq*64*2);
  unsigned short* ao     = (unsigned short*)alloc((size_t)Bb*Tseq*DM*2);
  (void)ws_size; (void)in_sizes; (void)n_in; (void)out_size;

  const int nx  = Bb*Tseq*DM;
  const int nqw = 3*DM*DM;
  const int now = DM*DM;
  k_convert<<<2048, 256, 0, stream>>>(x, x_bf, nx);
  k_convert<<<2048, 256, 0, stream>>>(qkvw, qw_bf, nqw);
  k_convert<<<1024, 256, 0, stream>>>(outw, ow_bf, now);
  // qkv GEMM with fused RoPE epilogue (writes qr, kr directly; v -> qkv_bf)
  k_gemm_bt<2><<<768, 256, 0, stream>>>(x_bf, qw_bf, qkv_bf, Bb*Tseq, 3*DM, DM, 3, qr, kr);
  k_vtrans<<<Bb*NH*(Tseq/64), 256, 0, stream>>>(qkv_bf, vt);
  k_attn<<<dim3(Bb*NH*16), 256, 0, stream>>>(qr, kr, vt, ao);
  k_gemm_bt<0><<<256, 256, 0, stream>>>(ao, ow_bf, out, Bb*Tseq, DM, DM, 1, qr, kr);
}

// Round 14
// 121.974 us; speedup vs baseline: 1.0609x; 1.0609x over previous
//
#include <hip/hip_runtime.h>
#include <hip/hip_bf16.h>
#include <cmath>

#define Bb   2
#define Tseq 2048
#define NH   16
#define DM   1024

using f32x4 = __attribute__((ext_vector_type(4))) float;
using s16x8 = __attribute__((ext_vector_type(8))) short;
using s16x4 = __attribute__((ext_vector_type(4))) short;

typedef const __attribute__((address_space(1))) unsigned char* as1p;
typedef __attribute__((address_space(3))) unsigned char* as3p;

static __device__ __forceinline__ void gload_lds16(const void* g, void* l){
  __builtin_amdgcn_global_load_lds((as1p)g, (as3p)l, 16, 0, 0);
}

// PV MFMA: 16x16x16 bf16 (K=16). B-frag needs P[k=g*4+j][q=ln] == QK^T output s[nt][r].
#if defined(__has_builtin)
#if __has_builtin(__builtin_amdgcn_mfma_f32_16x16x16bf16_1k)
#define MFMA16(acc, va, pb) (acc) = __builtin_amdgcn_mfma_f32_16x16x16bf16_1k((va), (pb), (acc), 0, 0, 0)
#endif
#endif
#ifndef MFMA16
#define MFMA16(acc, va, pb) asm volatile("s_nop 1\n\tv_mfma_f32_16x16x16_bf16 %0, %1, %2, %0" : "+v"(acc) : "v"(va), "v"(pb))
#endif

static __device__ __forceinline__ float b2f(unsigned short u){
  union { unsigned int u; float f; } v; v.u = ((unsigned int)u) << 16; return v.f;
}
static __device__ __forceinline__ unsigned short f2b(float f){
  union { float f; unsigned int u; } v; v.f = f;
  unsigned int u = v.u;
  return (unsigned short)((u + 0x7fffu + ((u >> 16) & 1u)) >> 16);
}

// ---------------- fp32 -> bf16 convert ----------------
__global__ void k_convert(const float* __restrict__ in, unsigned short* __restrict__ out, int n){
  int stride = gridDim.x * blockDim.x;
  for (int i = blockIdx.x * blockDim.x + threadIdx.x; i * 4 < n; i += stride) {
    const float4 v = *reinterpret_cast<const float4*>(in + (size_t)i * 4);
    ushort4 o; o.x = f2b(v.x); o.y = f2b(v.y); o.z = f2b(v.z); o.w = f2b(v.w);
    *reinterpret_cast<ushort4*>(out + (size_t)i * 4) = o;
  }
}

// ---------------- GEMM  C[m,n] = sum_k A[m,k] * W[n,k] ----------------
// BK=64, gload_lds w16 with pre-swizzled SOURCE (linear dest + inverse-swz src
// + swz read; 0 bank conflicts verified r11). XCD-chunked 1D grid.
// MODE 0: fp32 C out. MODE 2: qkv fused epilogue -- q/k get in-register RoPE
// (on-the-fly __sincosf); q scaled by 0.125*log2(e) so attn can use exp2.
template<int MODE>
__global__ __launch_bounds__(256) void k_gemm_bt(const unsigned short* __restrict__ A,
                                                 const unsigned short* __restrict__ W,
                                                 void* __restrict__ Cout,
                                                 int M, int N, int K, int NYL,
                                                 unsigned short* __restrict__ qr,
                                                 unsigned short* __restrict__ kr){
  __shared__ unsigned short As[128*64];
  __shared__ unsigned short Bs[128*64];
  const int i = (int)blockIdx.x;
  const int xcd = i & 7, rr = i >> 3;
  const int bx = rr / NYL, by = xcd * NYL + (rr % NYL);
  const int bm = bx * 128, bn = by * 128;
  const int tid = threadIdx.x;
  const int lane = tid & 63, w = tid >> 6;
  const int wr = w >> 1, wc = w & 1;            // wave -> 64x64 quadrant
  const int g = lane >> 4, ln = lane & 15;
  f32x4 acc[4][4] = {};
  char* asb = (char*)As + w * 4096;
  char* bsb = (char*)Bs + w * 4096;
  const int lrow8 = lane >> 3;                   // 0..7: row within 8-row gload group
  const int kcolb = ((lane & 7) ^ lrow8) * 16;   // byte col in 128B row window, pre-swz
  const size_t aro = (size_t)(bm + w * 32 + lrow8) * K;
  const size_t bro = (size_t)(bn + w * 32 + lrow8) * K;
  const int xr = (ln & 7) << 4;                  // read-side XOR (row&7 == ln&7)
  for (int k0 = 0; k0 < K; k0 += 64) {
    #pragma unroll
    for (int q4 = 0; q4 < 4; ++q4) {
      gload_lds16((const char*)(A + aro + (size_t)(q4 * 8) * K + k0) + kcolb, asb + q4 * 1024);
      gload_lds16((const char*)(W + bro + (size_t)(q4 * 8) * K + k0) + kcolb, bsb + q4 * 1024);
    }
    __syncthreads();
    #pragma unroll
    for (int kk = 0; kk < 2; ++kk) {
      s16x8 af[4], bfr[4];
      const int ro = (kk * 64 + g * 16) ^ xr;
      #pragma unroll
      for (int mt = 0; mt < 4; ++mt)
        af[mt] = *reinterpret_cast<const s16x8*>((char*)As + (wr*64 + mt*16 + ln) * 128 + ro);
      #pragma unroll
      for (int nt = 0; nt < 4; ++nt)
        bfr[nt] = *reinterpret_cast<const s16x8*>((char*)Bs + (wc*64 + nt*16 + ln) * 128 + ro);
      #pragma unroll
      for (int mt = 0; mt < 4; ++mt)
        #pragma unroll
        for (int nt = 0; nt < 4; ++nt)
          acc[mt][nt] = __builtin_amdgcn_mfma_f32_16x16x32_bf16(af[mt], bfr[nt], acc[mt][nt], 0, 0, 0);
    }
    __syncthreads();
  }
  // ---------------- epilogue ----------------
  if (MODE == 0) {
    #pragma unroll
    for (int mt = 0; mt < 4; ++mt)
      #pragma unroll
      for (int nt = 0; nt < 4; ++nt)
        #pragma unroll
        for (int r = 0; r < 4; ++r) {
          int row = bm + wr*64 + mt*16 + g*4 + r;     // D: row = (lane>>4)*4 + reg
          int col = bn + wc*64 + nt*16 + ln;          // D: col = lane&15
          reinterpret_cast<float*>(Cout)[(size_t)row * N + col] = acc[mt][nt][r];
        }
  } else {
    const int region = bn >> 10;                      // 0=q, 1=k, 2=v
    if (region == 2) {
      #pragma unroll
      for (int mt = 0; mt < 4; ++mt)
        #pragma unroll
        for (int nt = 0; nt < 4; ++nt)
          #pragma unroll
          for (int r = 0; r < 4; ++r) {
            int row = bm + wr*64 + mt*16 + g*4 + r;
            int col = bn + wc*64 + nt*16 + ln;
            reinterpret_cast<unsigned short*>(Cout)[(size_t)row * N + col] = f2b(acc[mt][nt][r]);
          }
    } else {
      // RoPE in-register: dd = nt*16+ln (wc-independent); pairs (nt, nt^2) same lane.
      const float if0 = exp2f(-(float)ln        * 0.4152410118074f);
      const float if1 = exp2f(-(float)(16 + ln) * 0.4152410118074f);
      const int h = ((bn + wc * 64) >> 6) & 15;
      unsigned short* dst = (region == 0) ? qr : kr;
      // q: fold 1/sqrt(dh) AND log2(e) so attention uses native exp2
      const float qs = (region == 0) ? 0.18033688011112042f : 1.0f;
      #pragma unroll
      for (int mt = 0; mt < 4; ++mt)
        #pragma unroll
        for (int r = 0; r < 4; ++r) {
          int row = bm + wr*64 + mt*16 + g*4 + r;
          int t = row & (Tseq - 1), b = row >> 11;
          float c0, s0, c1, s1;
          __sincosf((float)t * if0, &s0, &c0);
          __sincosf((float)t * if1, &s1, &c1);
          float v0 = (acc[mt][0][r] * c0 - acc[mt][2][r] * s0) * qs;  // dd=ln
          float v1 = (acc[mt][1][r] * c1 - acc[mt][3][r] * s1) * qs;  // dd=16+ln
          float v2 = (acc[mt][2][r] * c0 + acc[mt][0][r] * s0) * qs;  // dd=32+ln
          float v3 = (acc[mt][3][r] * c1 + acc[mt][1][r] * s1) * qs;  // dd=48+ln
          size_t base = ((size_t)(b * NH + h) * Tseq + t) * 64 + ln;
          dst[base]      = f2b(v0);
          dst[base + 16] = f2b(v1);
          dst[base + 32] = f2b(v2);
          dst[base + 48] = f2b(v3);
        }
    }
  }
}

// ---------------- V transpose: qkv[b,t,2048+h*64+d] -> vt[b,h,d,t], LDS-tiled ----------------
__global__ __launch_bounds__(256) void k_vtrans(const unsigned short* __restrict__ qkv,
                                                unsigned short* __restrict__ vt){
  __shared__ unsigned short L[64*72];               // stride 72 shorts (144B, 16B-aligned)
  const int blk = blockIdx.x;                       // bh*32 + ttile
  const int tt64 = blk & 31, bh = blk >> 5;
  const int b = bh >> 4, h = bh & 15;
  const int t0 = tt64 * 64;
  const int tid = threadIdx.x;
  {
    const int tr = tid >> 2, c = tid & 3;           // row t, 16-short chunk
    const unsigned short* src = qkv + ((size_t)(b * Tseq) + t0 + tr) * 3072 + 2048 + h * 64 + c * 16;
    uint4 a0 = *reinterpret_cast<const uint4*>(src);
    uint4 a1 = *reinterpret_cast<const uint4*>(src + 8);
    *reinterpret_cast<uint4*>(&L[tr * 72 + c * 16])     = a0;
    *reinterpret_cast<uint4*>(&L[tr * 72 + c * 16 + 8]) = a1;
  }
  __syncthreads();
  {
    const int d = tid >> 2, c = tid & 3;            // row d, 16-t chunk
    unsigned int wq[8];
    #pragma unroll
    for (int j = 0; j < 8; ++j) {
      unsigned int lo = L[(c * 16 + 2 * j)     * 72 + d];
      unsigned int hi = L[(c * 16 + 2 * j + 1) * 72 + d];
      wq[j] = lo | (hi << 16);
    }
    unsigned short* dst = vt + ((size_t)bh * 64 + d) * Tseq + t0 + c * 16;
    *reinterpret_cast<uint4*>(dst)     = make_uint4(wq[0], wq[1], wq[2], wq[3]);
    *reinterpret_cast<uint4*>(dst + 8) = make_uint4(wq[4], wq[5], wq[6], wq[7]);
  }
}

// ---------------- causal flash attention, fully-swapped, dbuf + reg-P ----------------
// 256-thr blocks (4 waves x 16 q), paired q-tiles (j, 31-j): 33 visits, 512 blocks
// = 2/CU, XCD-chunked (4 heads/XCD L2-resident). K reg-staged (16B-granular swizzle,
// r12-proven); V reg-staged with fine swizzle ((row&7)<<4 | row&8) so PV b64 reads
// cover all 16 bank-pairs per quarter. QK^T: 16x16x32 swapped. PV: 16x16x16,
// P in registers (exp2 + trunc-pack).
__global__ __launch_bounds__(256, 2) void k_attn(const unsigned short* __restrict__ Qr,
                                                 const unsigned short* __restrict__ Kr,
                                                 const unsigned short* __restrict__ Vt,
                                                 unsigned short* __restrict__ Ao){
  __shared__ unsigned short Ks[2][64*64];
  __shared__ unsigned short Vs[2][64*64];
  __shared__ unsigned short Ps[4][16*72];
  // XCD-chunked bijective remap: 512 = 8 xcds x (4 heads x 16 pj)
  const int i = (int)blockIdx.x;
  const int xcd = i & 7, r = i >> 3;
  const int bh = xcd * 4 + (r >> 4);
  const int pj = r & 15;
  const unsigned short* Q  = Qr + (size_t)bh * Tseq * 64;
  const unsigned short* Kp = Kr + (size_t)bh * Tseq * 64;
  const unsigned short* Vp = Vt + (size_t)bh * 64 * Tseq;
  const int tid = threadIdx.x;
  const int w = tid >> 6, lane = tid & 63;
  const int g = lane >> 4, ln = lane & 15;
  // staging: 256 thr x 32B of each 8KB tile. row = tid>>2, chunk pair = (tid&3)*2
  const int srow = tid >> 2;
  const int c2 = (tid & 3) * 2;
  const int scol = c2 * 8;                          // shorts
  // K: 16B-granular swizzle (r12-proven)
  const int kswz = (srow & 7) << 4;
  const int kb0 = srow * 128 + ((c2 * 16)      ^ kswz);
  const int kb1 = srow * 128 + ((c2 * 16 + 16) ^ kswz);
  // V: fine swizzle incl. bit3 (conflict-free PV b64 reads, verified r13)
  const int vswz = ((srow & 7) << 4) | (srow & 8);
  const int vb0 = srow * 128 + ((c2 * 16)      ^ vswz);
  const int vb1 = srow * 128 + ((c2 * 16 + 8)  ^ vswz);
  const int vb2 = srow * 128 + ((c2 * 16 + 16) ^ vswz);
  const int vb3 = srow * 128 + ((c2 * 16 + 24) ^ vswz);
  // QK frag read offsets (K buffer)
  const int x0 = (g * 16)      ^ ((ln & 7) << 4);
  const int x1 = (64 + g * 16) ^ ((ln & 7) << 4);
  // PV frag read swizzle (V buffer, fine)
  const int pvswz = ((ln & 7) << 4) | (ln & 8);
  unsigned short* Pw = Ps[w];
  const int b = bh / NH, h = bh % NH;

  #pragma unroll
  for (int pass = 0; pass < 2; ++pass) {
    const int j = pass ? (31 - pj) : pj;            // paired q-tiles: 33 visits total
    const int q0 = j * 64;
    const int ntiles = j + 1;
    const int q0w = q0 + w * 16;

    s16x8 qf0 = *reinterpret_cast<const s16x8*>(&Q[(size_t)(q0w + ln) * 64 + g * 8]);
    s16x8 qf1 = *reinterpret_cast<const s16x8*>(&Q[(size_t)(q0w + ln) * 64 + 32 + g * 8]);

    f32x4 oacc[4] = {};
    float lsum = 0.f;

    // prologue: stage tile 0 into buf 0
    {
      const unsigned short* gk = Kp + (size_t)srow * 64 + scol;
      const unsigned short* gv = Vp + (size_t)srow * Tseq + scol;
      uint4 k0 = *reinterpret_cast<const uint4*>(gk);
      uint4 k1 = *reinterpret_cast<const uint4*>(gk + 8);
      uint4 v0 = *reinterpret_cast<const uint4*>(gv);
      uint4 v1 = *reinterpret_cast<const uint4*>(gv + 8);
      *reinterpret_cast<uint4*>((char*)Ks[0] + kb0) = k0;
      *reinterpret_cast<uint4*>((char*)Ks[0] + kb1) = k1;
      *reinterpret_cast<uint2*>((char*)Vs[0] + vb0) = make_uint2(v0.x, v0.y);
      *reinterpret_cast<uint2*>((char*)Vs[0] + vb1) = make_uint2(v0.z, v0.w);
      *reinterpret_cast<uint2*>((char*)Vs[0] + vb2) = make_uint2(v1.x, v1.y);
      *reinterpret_cast<uint2*>((char*)Vs[0] + vb3) = make_uint2(v1.z, v1.w);
    }
    __syncthreads();
    int cur = 0;

    for (int kt = 0; kt < ntiles; ++kt) {
      const bool pre = (kt + 1 < ntiles);
      const int nxt = cur ^ 1;
      uint4 nk0, nk1, nv0, nv1;
      if (pre) {  // issue next-tile loads early; L2-hit latency hides under compute
        const unsigned short* gk = Kp + (size_t)((kt + 1) * 64 + srow) * 64 + scol;
        const unsigned short* gv = Vp + (size_t)srow * Tseq + (kt + 1) * 64 + scol;
        nk0 = *reinterpret_cast<const uint4*>(gk);
        nk1 = *reinterpret_cast<const uint4*>(gk + 8);
        nv0 = *reinterpret_cast<const uint4*>(gv);
        nv1 = *reinterpret_cast<const uint4*>(gv + 8);
      }
      // ---- QK^T swapped: s[nt] = S^T[k = kt*64+nt*16+g*4+r][q = q0w+ln] ----
      f32x4 s[4] = {};
      const char* kb = (const char*)Ks[cur];
      __builtin_amdgcn_s_setprio(1);
      #pragma unroll
      for (int nt = 0; nt < 4; ++nt) {
        s16x8 kfa = *reinterpret_cast<const s16x8*>(kb + nt * 2048 + ln * 128 + x0);
        s16x8 kfb = *reinterpret_cast<const s16x8*>(kb + nt * 2048 + ln * 128 + x1);
        s[nt] = __builtin_amdgcn_mfma_f32_16x16x32_bf16(kfa, qf0, s[nt], 0, 0, 0);
        s[nt] = __builtin_amdgcn_mfma_f32_16x16x32_bf16(kfb, qf1, s[nt], 0, 0, 0);
      }
      __builtin_amdgcn_s_setprio(0);
      // ---- causal mask (last tile only; k_rel = nt*16+g*4+r, q_rel = w*16+ln) ----
      if (kt == ntiles - 1) {
        #pragma unroll
        for (int nt = 0; nt < 4; ++nt)
          #pragma unroll
          for (int r2 = 0; r2 < 4; ++r2)
            if (nt * 16 + g * 4 + r2 > w * 16 + ln) s[nt][r2] = -1e30f;
      }
      // ---- fixed-base softmax in exp2 domain (q pre-scaled by log2e/8);
      //      P packed to bf16 by truncation (P-only; tolerance has ~3x headroom) ----
      s16x4 pb[4];
      #pragma unroll
      for (int nt = 0; nt < 4; ++nt)
        #pragma unroll
        for (int r2 = 0; r2 < 4; ++r2) {
          float p = exp2f(s[nt][r2]);
          lsum += p;
          pb[nt][r2] = (short)(__float_as_uint(p) >> 16);
        }
      // ---- PV via 16x16x16: oacc[dt] = O^T[d = dt*16+g*4+r][q = ln] ----
      const char* vb = (const char*)Vs[cur];
      __builtin_amdgcn_s_setprio(1);
      #pragma unroll
      for (int dt = 0; dt < 4; ++dt) {
        #pragma unroll
        for (int nt = 0; nt < 4; ++nt) {
          s16x4 va = *reinterpret_cast<const s16x4*>(vb + (dt * 16 + ln) * 128 + ((nt * 32 + g * 8) ^ pvswz));
          MFMA16(oacc[dt], va, pb[nt]);
        }
      }
      __builtin_amdgcn_s_setprio(0);
      // ---- write prefetched tile into other buffer; single barrier ----
      if (pre) {
        *reinterpret_cast<uint4*>((char*)Ks[nxt] + kb0) = nk0;
        *reinterpret_cast<uint4*>((char*)Ks[nxt] + kb1) = nk1;
        *reinterpret_cast<uint2*>((char*)Vs[nxt] + vb0) = make_uint2(nv0.x, nv0.y);
        *reinterpret_cast<uint2*>((char*)Vs[nxt] + vb1) = make_uint2(nv0.z, nv0.w);
        *reinterpret_cast<uint2*>((char*)Vs[nxt] + vb2) = make_uint2(nv1.x, nv1.y);
        *reinterpret_cast<uint2*>((char*)Vs[nxt] + vb3) = make_uint2(nv1.z, nv1.w);
      }
      __syncthreads();
      cur ^= 1;
    }

    // ---- epilogue: l-reduce, O^T -> row-major via LDS bounce, coalesced stores ----
    float l = lsum;
    l += __shfl_xor(l, 16);
    l += __shfl_xor(l, 32);
    float inv = 1.f / l;
    #pragma unroll
    for (int nt = 0; nt < 4; ++nt) {
      unsigned int lo = (unsigned int)f2b(oacc[nt][0] * inv) | ((unsigned int)f2b(oacc[nt][1] * inv) << 16);
      unsigned int hi = (unsigned int)f2b(oacc[nt][2] * inv) | ((unsigned int)f2b(oacc[nt][3] * inv) << 16);
      *reinterpret_cast<uint2*>(&Pw[ln * 72 + nt * 16 + g * 4]) = make_uint2(lo, hi);
    }
    asm volatile("s_waitcnt lgkmcnt(0)" ::: "memory");
    __builtin_amdgcn_sched_barrier(0);
    const int rr = lane >> 2;                 // 0..15: q-row within wave tile
    const int cc = (lane & 3) * 8;            // short offset
    uint4 ov0 = *reinterpret_cast<const uint4*>(&Pw[rr * 72 + cc]);
    uint4 ov1 = *reinterpret_cast<const uint4*>(&Pw[rr * 72 + cc + 32]);
    int t = q0w + rr;
    unsigned short* orow = &Ao[((size_t)(b * Tseq + t) * DM) + h * 64];
    *reinterpret_cast<uint4*>(orow + cc)      = ov0;
    *reinterpret_cast<uint4*>(orow + cc + 32) = ov1;
  }
}

extern "C" void kernel_launch(void* const* d_in, const int* in_sizes, int n_in,
                              void* d_out, int out_size, void* d_ws, size_t ws_size,
                              hipStream_t stream) {
  const float* x    = (const float*)d_in[0];
  const float* qkvw = (const float*)d_in[1];
  const float* outw = (const float*)d_in[2];
  float* out = (float*)d_out;
  char* ws = (char*)d_ws;
  size_t off = 0;
  auto alloc = [&](size_t bytes)->void*{ void* p = ws + off; off += (bytes + 255) & ~(size_t)255; return p; };
  unsigned short* x_bf   = (unsigned short*)alloc((size_t)Bb*Tseq*DM*2);
  unsigned short* qw_bf  = (unsigned short*)alloc((size_t)3*DM*DM*2);
  unsigned short* ow_bf  = (unsigned short*)alloc((size_t)DM*DM*2);
  unsigned short* qkv_bf = (unsigned short*)alloc((size_t)Bb*Tseq*3*DM*2);
  unsigned short* qr     = (unsigned short*)alloc((size_t)Bb*NH*Tseq*64*2);
  unsigned short* kr     = (unsigned short*)alloc((size_t)Bb*NH*Tseq*64*2);
  unsigned short* vt     = (unsigned short*)alloc((size_t)Bb*NH*Tseq*64*2);
  unsigned short* ao     = (unsigned short*)alloc((size_t)Bb*Tseq*DM*2);
  (void)ws_size; (void)in_sizes; (void)n_in; (void)out_size;

  const int nx  = Bb*Tseq*DM;
  const int nqw = 3*DM*DM;
  const int now = DM*DM;
  k_convert<<<2048, 256, 0, stream>>>(x, x_bf, nx);
  k_convert<<<2048, 256, 0, stream>>>(qkvw, qw_bf, nqw);
  k_convert<<<1024, 256, 0, stream>>>(outw, ow_bf, now);
  // qkv GEMM with fused RoPE epilogue (writes qr, kr directly; v -> qkv_bf)
  k_gemm_bt<2><<<768, 256, 0, stream>>>(x_bf, qw_bf, qkv_bf, Bb*Tseq, 3*DM, DM, 3, qr, kr);
  k_vtrans<<<Bb*NH*(Tseq/64), 256, 0, stream>>>(qkv_bf, vt);
  k_attn<<<dim3(Bb*NH*16), 256, 0, stream>>>(qr, kr, vt, ao);
  k_gemm_bt<0><<<256, 256, 0, stream>>>(ao, ow_bf, out, Bb*Tseq, DM, DM, 1, qr, kr);
}

// Round 15
// 114.526 us; speedup vs baseline: 1.1299x; 1.0650x over previous
//
#include <hip/hip_runtime.h>
#include <hip/hip_bf16.h>
#include <cmath>

#define Bb   2
#define Tseq 2048
#define NH   16
#define DM   1024

using f32x4 = __attribute__((ext_vector_type(4))) float;
using s16x8 = __attribute__((ext_vector_type(8))) short;
using s16x4 = __attribute__((ext_vector_type(4))) short;

typedef const __attribute__((address_space(1))) unsigned char* as1p;
typedef __attribute__((address_space(3))) unsigned char* as3p;

static __device__ __forceinline__ void gload_lds16(const void* g, void* l){
  __builtin_amdgcn_global_load_lds((as1p)g, (as3p)l, 16, 0, 0);
}

// PV MFMA: 16x16x16 bf16 (K=16). B-frag needs P[k=g*4+j][q=ln] == QK^T output s[nt][r].
#if defined(__has_builtin)
#if __has_builtin(__builtin_amdgcn_mfma_f32_16x16x16bf16_1k)
#define MFMA16(acc, va, pb) (acc) = __builtin_amdgcn_mfma_f32_16x16x16bf16_1k((va), (pb), (acc), 0, 0, 0)
#endif
#endif
#ifndef MFMA16
#define MFMA16(acc, va, pb) asm volatile("s_nop 1\n\tv_mfma_f32_16x16x16_bf16 %0, %1, %2, %0" : "+v"(acc) : "v"(va), "v"(pb))
#endif

static __device__ __forceinline__ float b2f(unsigned short u){
  union { unsigned int u; float f; } v; v.u = ((unsigned int)u) << 16; return v.f;
}
static __device__ __forceinline__ unsigned short f2b(float f){
  union { float f; unsigned int u; } v; v.f = f;
  unsigned int u = v.u;
  return (unsigned short)((u + 0x7fffu + ((u >> 16) & 1u)) >> 16);
}

// ---------------- fp32 -> bf16 convert ----------------
__global__ void k_convert(const float* __restrict__ in, unsigned short* __restrict__ out, int n){
  int stride = gridDim.x * blockDim.x;
  for (int i = blockIdx.x * blockDim.x + threadIdx.x; i * 4 < n; i += stride) {
    const float4 v = *reinterpret_cast<const float4*>(in + (size_t)i * 4);
    ushort4 o; o.x = f2b(v.x); o.y = f2b(v.y); o.z = f2b(v.z); o.w = f2b(v.w);
    *reinterpret_cast<ushort4*>(out + (size_t)i * 4) = o;
  }
}

// ---------------- GEMM  C[m,n] = sum_k A[m,k] * W[n,k] ----------------
// BK=64, gload_lds w16 with pre-swizzled SOURCE (linear dest + inverse-swz src
// + swz read; 0 bank conflicts verified r11). XCD-chunked 1D grid.
// MODE 0: fp32 C out. MODE 2: qkv fused epilogue -- q/k get in-register RoPE
// (on-the-fly __sincosf); q scaled by 0.125*log2(e) so attn can use exp2.
template<int MODE>
__global__ __launch_bounds__(256) void k_gemm_bt(const unsigned short* __restrict__ A,
                                                 const unsigned short* __restrict__ W,
                                                 void* __restrict__ Cout,
                                                 int M, int N, int K, int NYL,
                                                 unsigned short* __restrict__ qr,
                                                 unsigned short* __restrict__ kr){
  __shared__ unsigned short As[128*64];
  __shared__ unsigned short Bs[128*64];
  const int i = (int)blockIdx.x;
  const int xcd = i & 7, rr = i >> 3;
  const int bx = rr / NYL, by = xcd * NYL + (rr % NYL);
  const int bm = bx * 128, bn = by * 128;
  const int tid = threadIdx.x;
  const int lane = tid & 63, w = tid >> 6;
  const int wr = w >> 1, wc = w & 1;            // wave -> 64x64 quadrant
  const int g = lane >> 4, ln = lane & 15;
  f32x4 acc[4][4] = {};
  char* asb = (char*)As + w * 4096;
  char* bsb = (char*)Bs + w * 4096;
  const int lrow8 = lane >> 3;                   // 0..7: row within 8-row gload group
  const int kcolb = ((lane & 7) ^ lrow8) * 16;   // byte col in 128B row window, pre-swz
  const size_t aro = (size_t)(bm + w * 32 + lrow8) * K;
  const size_t bro = (size_t)(bn + w * 32 + lrow8) * K;
  const int xr = (ln & 7) << 4;                  // read-side XOR (row&7 == ln&7)
  for (int k0 = 0; k0 < K; k0 += 64) {
    #pragma unroll
    for (int q4 = 0; q4 < 4; ++q4) {
      gload_lds16((const char*)(A + aro + (size_t)(q4 * 8) * K + k0) + kcolb, asb + q4 * 1024);
      gload_lds16((const char*)(W + bro + (size_t)(q4 * 8) * K + k0) + kcolb, bsb + q4 * 1024);
    }
    __syncthreads();
    #pragma unroll
    for (int kk = 0; kk < 2; ++kk) {
      s16x8 af[4], bfr[4];
      const int ro = (kk * 64 + g * 16) ^ xr;
      #pragma unroll
      for (int mt = 0; mt < 4; ++mt)
        af[mt] = *reinterpret_cast<const s16x8*>((char*)As + (wr*64 + mt*16 + ln) * 128 + ro);
      #pragma unroll
      for (int nt = 0; nt < 4; ++nt)
        bfr[nt] = *reinterpret_cast<const s16x8*>((char*)Bs + (wc*64 + nt*16 + ln) * 128 + ro);
      #pragma unroll
      for (int mt = 0; mt < 4; ++mt)
        #pragma unroll
        for (int nt = 0; nt < 4; ++nt)
          acc[mt][nt] = __builtin_amdgcn_mfma_f32_16x16x32_bf16(af[mt], bfr[nt], acc[mt][nt], 0, 0, 0);
    }
    __syncthreads();
  }
  // ---------------- epilogue ----------------
  if (MODE == 0) {
    #pragma unroll
    for (int mt = 0; mt < 4; ++mt)
      #pragma unroll
      for (int nt = 0; nt < 4; ++nt)
        #pragma unroll
        for (int r = 0; r < 4; ++r) {
          int row = bm + wr*64 + mt*16 + g*4 + r;     // D: row = (lane>>4)*4 + reg
          int col = bn + wc*64 + nt*16 + ln;          // D: col = lane&15
          reinterpret_cast<float*>(Cout)[(size_t)row * N + col] = acc[mt][nt][r];
        }
  } else {
    const int region = bn >> 10;                      // 0=q, 1=k, 2=v
    if (region == 2) {
      #pragma unroll
      for (int mt = 0; mt < 4; ++mt)
        #pragma unroll
        for (int nt = 0; nt < 4; ++nt)
          #pragma unroll
          for (int r = 0; r < 4; ++r) {
            int row = bm + wr*64 + mt*16 + g*4 + r;
            int col = bn + wc*64 + nt*16 + ln;
            reinterpret_cast<unsigned short*>(Cout)[(size_t)row * N + col] = f2b(acc[mt][nt][r]);
          }
    } else {
      // RoPE in-register: dd = nt*16+ln (wc-independent); pairs (nt, nt^2) same lane.
      const float if0 = exp2f(-(float)ln        * 0.4152410118074f);
      const float if1 = exp2f(-(float)(16 + ln) * 0.4152410118074f);
      const int h = ((bn + wc * 64) >> 6) & 15;
      unsigned short* dst = (region == 0) ? qr : kr;
      // q: fold 1/sqrt(dh) AND log2(e) so attention uses native exp2
      const float qs = (region == 0) ? 0.18033688011112042f : 1.0f;
      #pragma unroll
      for (int mt = 0; mt < 4; ++mt)
        #pragma unroll
        for (int r = 0; r < 4; ++r) {
          int row = bm + wr*64 + mt*16 + g*4 + r;
          int t = row & (Tseq - 1), b = row >> 11;
          float c0, s0, c1, s1;
          __sincosf((float)t * if0, &s0, &c0);
          __sincosf((float)t * if1, &s1, &c1);
          float v0 = (acc[mt][0][r] * c0 - acc[mt][2][r] * s0) * qs;  // dd=ln
          float v1 = (acc[mt][1][r] * c1 - acc[mt][3][r] * s1) * qs;  // dd=16+ln
          float v2 = (acc[mt][2][r] * c0 + acc[mt][0][r] * s0) * qs;  // dd=32+ln
          float v3 = (acc[mt][3][r] * c1 + acc[mt][1][r] * s1) * qs;  // dd=48+ln
          size_t base = ((size_t)(b * NH + h) * Tseq + t) * 64 + ln;
          dst[base]      = f2b(v0);
          dst[base + 16] = f2b(v1);
          dst[base + 32] = f2b(v2);
          dst[base + 48] = f2b(v3);
        }
    }
  }
}

// ---------------- V transpose: qkv[b,t,2048+h*64+d] -> vt[b,h,d,t], LDS-tiled ----------------
__global__ __launch_bounds__(256) void k_vtrans(const unsigned short* __restrict__ qkv,
                                                unsigned short* __restrict__ vt){
  __shared__ unsigned short L[64*72];               // stride 72 shorts (144B, 16B-aligned)
  const int blk = blockIdx.x;                       // bh*32 + ttile
  const int tt64 = blk & 31, bh = blk >> 5;
  const int b = bh >> 4, h = bh & 15;
  const int t0 = tt64 * 64;
  const int tid = threadIdx.x;
  {
    const int tr = tid >> 2, c = tid & 3;           // row t, 16-short chunk
    const unsigned short* src = qkv + ((size_t)(b * Tseq) + t0 + tr) * 3072 + 2048 + h * 64 + c * 16;
    uint4 a0 = *reinterpret_cast<const uint4*>(src);
    uint4 a1 = *reinterpret_cast<const uint4*>(src + 8);
    *reinterpret_cast<uint4*>(&L[tr * 72 + c * 16])     = a0;
    *reinterpret_cast<uint4*>(&L[tr * 72 + c * 16 + 8]) = a1;
  }
  __syncthreads();
  {
    const int d = tid >> 2, c = tid & 3;            // row d, 16-t chunk
    unsigned int wq[8];
    #pragma unroll
    for (int j = 0; j < 8; ++j) {
      unsigned int lo = L[(c * 16 + 2 * j)     * 72 + d];
      unsigned int hi = L[(c * 16 + 2 * j + 1) * 72 + d];
      wq[j] = lo | (hi << 16);
    }
    unsigned short* dst = vt + ((size_t)bh * 64 + d) * Tseq + t0 + c * 16;
    *reinterpret_cast<uint4*>(dst)     = make_uint4(wq[0], wq[1], wq[2], wq[3]);
    *reinterpret_cast<uint4*>(dst + 8) = make_uint4(wq[4], wq[5], wq[6], wq[7]);
  }
}

// ---------------- causal flash attention, fully-swapped, dbuf + reg-P (r12 structure) ----------------
// 256-thr blocks (4 waves x 16 q), paired q-tiles (j, 31-j): 33 visits, 512 blocks
// = 2/CU, XCD-chunked (4 heads/XCD L2-resident). K/V reg-staged, 16B-granular swizzle
// (r12-proven layout; PV b64 conflicts accepted -- they are latency-hidden at 2 blk/CU,
// r13/r14 showed "fixing" them costs more than it saves). QK^T: 16x16x32 swapped.
// PV: 16x16x16, P in registers. exp2-domain softmax (raw v_exp_f32) + trunc-pack.
__global__ __launch_bounds__(256, 2) void k_attn(const unsigned short* __restrict__ Qr,
                                                 const unsigned short* __restrict__ Kr,
                                                 const unsigned short* __restrict__ Vt,
                                                 unsigned short* __restrict__ Ao){
  __shared__ unsigned short Ks[2][64*64];
  __shared__ unsigned short Vs[2][64*64];
  __shared__ unsigned short Ps[4][16*72];
  // XCD-chunked bijective remap: 512 = 8 xcds x (4 heads x 16 pj)
  const int i = (int)blockIdx.x;
  const int xcd = i & 7, r = i >> 3;
  const int bh = xcd * 4 + (r >> 4);
  const int pj = r & 15;
  const unsigned short* Q  = Qr + (size_t)bh * Tseq * 64;
  const unsigned short* Kp = Kr + (size_t)bh * Tseq * 64;
  const unsigned short* Vp = Vt + (size_t)bh * 64 * Tseq;
  const int tid = threadIdx.x;
  const int w = tid >> 6, lane = tid & 63;
  const int g = lane >> 4, ln = lane & 15;
  // staging: 256 thr x 32B of each 8KB tile. row = tid>>2, chunk pair = (tid&3)*2
  const int srow = tid >> 2;
  const int c2 = (tid & 3) * 2;
  const int scol = c2 * 8;                          // shorts
  const int swz = (srow & 7) << 4;
  const int wb0 = srow * 128 + ((c2 * 16)      ^ swz);
  const int wb1 = srow * 128 + ((c2 * 16 + 16) ^ swz);
  // QK frag read offsets (b128)
  const int x0 = (g * 16)      ^ ((ln & 7) << 4);
  const int x1 = (64 + g * 16) ^ ((ln & 7) << 4);
  unsigned short* Pw = Ps[w];
  const int b = bh / NH, h = bh % NH;

  #pragma unroll
  for (int pass = 0; pass < 2; ++pass) {
    const int j = pass ? (31 - pj) : pj;            // paired q-tiles: 33 visits total
    const int q0 = j * 64;
    const int ntiles = j + 1;
    const int q0w = q0 + w * 16;

    s16x8 qf0 = *reinterpret_cast<const s16x8*>(&Q[(size_t)(q0w + ln) * 64 + g * 8]);
    s16x8 qf1 = *reinterpret_cast<const s16x8*>(&Q[(size_t)(q0w + ln) * 64 + 32 + g * 8]);

    f32x4 oacc[4] = {};
    float lsum = 0.f;

    // prologue: stage tile 0 into buf 0
    {
      const unsigned short* gk = Kp + (size_t)srow * 64 + scol;
      const unsigned short* gv = Vp + (size_t)srow * Tseq + scol;
      uint4 k0 = *reinterpret_cast<const uint4*>(gk);
      uint4 k1 = *reinterpret_cast<const uint4*>(gk + 8);
      uint4 v0 = *reinterpret_cast<const uint4*>(gv);
      uint4 v1 = *reinterpret_cast<const uint4*>(gv + 8);
      *reinterpret_cast<uint4*>((char*)Ks[0] + wb0) = k0;
      *reinterpret_cast<uint4*>((char*)Ks[0] + wb1) = k1;
      *reinterpret_cast<uint4*>((char*)Vs[0] + wb0) = v0;
      *reinterpret_cast<uint4*>((char*)Vs[0] + wb1) = v1;
    }
    __syncthreads();
    int cur = 0;

    for (int kt = 0; kt < ntiles; ++kt) {
      const bool pre = (kt + 1 < ntiles);
      const int nxt = cur ^ 1;
      uint4 nk0, nk1, nv0, nv1;
      if (pre) {  // issue next-tile loads early; L2-hit latency hides under compute
        const unsigned short* gk = Kp + (size_t)((kt + 1) * 64 + srow) * 64 + scol;
        const unsigned short* gv = Vp + (size_t)srow * Tseq + (kt + 1) * 64 + scol;
        nk0 = *reinterpret_cast<const uint4*>(gk);
        nk1 = *reinterpret_cast<const uint4*>(gk + 8);
        nv0 = *reinterpret_cast<const uint4*>(gv);
        nv1 = *reinterpret_cast<const uint4*>(gv + 8);
      }
      // ---- QK^T swapped: s[nt] = S^T[k = kt*64+nt*16+g*4+r][q = q0w+ln] ----
      f32x4 s[4] = {};
      const char* kb = (const char*)Ks[cur];
      __builtin_amdgcn_s_setprio(1);
      #pragma unroll
      for (int nt = 0; nt < 4; ++nt) {
        s16x8 kfa = *reinterpret_cast<const s16x8*>(kb + nt * 2048 + ln * 128 + x0);
        s16x8 kfb = *reinterpret_cast<const s16x8*>(kb + nt * 2048 + ln * 128 + x1);
        s[nt] = __builtin_amdgcn_mfma_f32_16x16x32_bf16(kfa, qf0, s[nt], 0, 0, 0);
        s[nt] = __builtin_amdgcn_mfma_f32_16x16x32_bf16(kfb, qf1, s[nt], 0, 0, 0);
      }
      __builtin_amdgcn_s_setprio(0);
      // ---- causal mask (last tile only; k_rel = nt*16+g*4+r, q_rel = w*16+ln) ----
      if (kt == ntiles - 1) {
        #pragma unroll
        for (int nt = 0; nt < 4; ++nt)
          #pragma unroll
          for (int r2 = 0; r2 < 4; ++r2)
            if (nt * 16 + g * 4 + r2 > w * 16 + ln) s[nt][r2] = -1e30f;
      }
      // ---- fixed-base softmax, exp2 domain (q pre-scaled by log2e/8);
      //      raw v_exp_f32 via builtin; P packed to bf16 by truncation ----
      s16x4 pb[4];
      #pragma unroll
      for (int nt = 0; nt < 4; ++nt)
        #pragma unroll
        for (int r2 = 0; r2 < 4; ++r2) {
          float p = __builtin_amdgcn_exp2f(s[nt][r2]);
          lsum += p;
          pb[nt][r2] = (short)(__float_as_uint(p) >> 16);
        }
      // ---- PV via 16x16x16: oacc[dt] = O^T[d = dt*16+g*4+r][q = ln] ----
      const char* vb = (const char*)Vs[cur];
      __builtin_amdgcn_s_setprio(1);
      #pragma unroll
      for (int dt = 0; dt < 4; ++dt) {
        #pragma unroll
        for (int nt = 0; nt < 4; ++nt) {
          s16x4 va = *reinterpret_cast<const s16x4*>(vb + (dt * 16 + ln) * 128 + ((nt * 32 + g * 8) ^ ((ln & 7) << 4)));
          MFMA16(oacc[dt], va, pb[nt]);
        }
      }
      __builtin_amdgcn_s_setprio(0);
      // ---- write prefetched tile into other buffer; single barrier ----
      if (pre) {
        *reinterpret_cast<uint4*>((char*)Ks[nxt] + wb0) = nk0;
        *reinterpret_cast<uint4*>((char*)Ks[nxt] + wb1) = nk1;
        *reinterpret_cast<uint4*>((char*)Vs[nxt] + wb0) = nv0;
        *reinterpret_cast<uint4*>((char*)Vs[nxt] + wb1) = nv1;
      }
      __syncthreads();
      cur ^= 1;
    }

    // ---- epilogue: l-reduce, O^T -> row-major via LDS bounce, coalesced stores ----
    float l = lsum;
    l += __shfl_xor(l, 16);
    l += __shfl_xor(l, 32);
    float inv = 1.f / l;
    #pragma unroll
    for (int nt = 0; nt < 4; ++nt) {
      unsigned int lo = (unsigned int)f2b(oacc[nt][0] * inv) | ((unsigned int)f2b(oacc[nt][1] * inv) << 16);
      unsigned int hi = (unsigned int)f2b(oacc[nt][2] * inv) | ((unsigned int)f2b(oacc[nt][3] * inv) << 16);
      *reinterpret_cast<uint2*>(&Pw[ln * 72 + nt * 16 + g * 4]) = make_uint2(lo, hi);
    }
    asm volatile("s_waitcnt lgkmcnt(0)" ::: "memory");
    __builtin_amdgcn_sched_barrier(0);
    const int rr = lane >> 2;                 // 0..15: q-row within wave tile
    const int cc = (lane & 3) * 8;            // short offset
    uint4 ov0 = *reinterpret_cast<const uint4*>(&Pw[rr * 72 + cc]);
    uint4 ov1 = *reinterpret_cast<const uint4*>(&Pw[rr * 72 + cc + 32]);
    int t = q0w + rr;
    unsigned short* orow = &Ao[((size_t)(b * Tseq + t) * DM) + h * 64];
    *reinterpret_cast<uint4*>(orow + cc)      = ov0;
    *reinterpret_cast<uint4*>(orow + cc + 32) = ov1;
  }
}

extern "C" void kernel_launch(void* const* d_in, const int* in_sizes, int n_in,
                              void* d_out, int out_size, void* d_ws, size_t ws_size,
                              hipStream_t stream) {
  const float* x    = (const float*)d_in[0];
  const float* qkvw = (const float*)d_in[1];
  const float* outw = (const float*)d_in[2];
  float* out = (float*)d_out;
  char* ws = (char*)d_ws;
  size_t off = 0;
  auto alloc = [&](size_t bytes)->void*{ void* p = ws + off; off += (bytes + 255) & ~(size_t)255; return p; };
  unsigned short* x_bf   = (unsigned short*)alloc((size_t)Bb*Tseq*DM*2);
  unsigned short* qw_bf  = (unsigned short*)alloc((size_t)3*DM*DM*2);
  unsigned short* ow_bf  = (unsigned short*)alloc((size_t)DM*DM*2);
  unsigned short* qkv_bf = (unsigned short*)alloc((size_t)Bb*Tseq*3*DM*2);
  unsigned short* qr     = (unsigned short*)alloc((size_t)Bb*NH*Tseq*64*2);
  unsigned short* kr     = (unsigned short*)alloc((size_t)Bb*NH*Tseq*64*2);
  unsigned short* vt     = (unsigned short*)alloc((size_t)Bb*NH*Tseq*64*2);
  unsigned short* ao     = (unsigned short*)alloc((size_t)Bb*Tseq*DM*2);
  (void)ws_size; (void)in_sizes; (void)n_in; (void)out_size;

  const int nx  = Bb*Tseq*DM;
  const int nqw = 3*DM*DM;
  const int now = DM*DM;
  k_convert<<<2048, 256, 0, stream>>>(x, x_bf, nx);
  k_convert<<<2048, 256, 0, stream>>>(qkvw, qw_bf, nqw);
  k_convert<<<1024, 256, 0, stream>>>(outw, ow_bf, now);
  // qkv GEMM with fused RoPE epilogue (writes qr, kr directly; v -> qkv_bf)
  k_gemm_bt<2><<<768, 256, 0, stream>>>(x_bf, qw_bf, qkv_bf, Bb*Tseq, 3*DM, DM, 3, qr, kr);
  k_vtrans<<<Bb*NH*(Tseq/64), 256, 0, stream>>>(qkv_bf, vt);
  k_attn<<<dim3(Bb*NH*16), 256, 0, stream>>>(qr, kr, vt, ao);
  k_gemm_bt<0><<<256, 256, 0, stream>>>(ao, ow_bf, out, Bb*Tseq, DM, DM, 1, qr, kr);
}